// Round 7
// baseline (3520.337 us; speedup 1.0000x reference)
//
#include <hip/hip_runtime.h>
#include <hip/hip_bf16.h>

// DenoisingPotential: x_{t+1} = x_t + alpha * grad_phi(x_t), 10 iters.
// s_k = e_k + (Pmu_k . x) - 0.5*(x . y_k), y_k = P_k x
// x += (alpha/l) * (sum_k wt_k Pmu_k - sum_k wt_k y_k), wt = exp(s), l = sum wt
//
// R7: four structures all hit ~1900 cyc/CU-k-step => latency-bound at the
// 2-waves/SIMD supply cap (8 waves/CU at 32 pts/wave). Fix: DIM-SPLIT wave
// pairs — each 32-pt group is served by two waves, wave d computing output
// dims [32d,32d+32): 16 waves/CU (4/SIMD), 4 KB P reads per wave-k-step,
// ~105 VGPRs (fits launch_bounds(256,4) without spilling). The xy dot's
// cross-wave partial is exchanged via parity-slotted LDS, pipelined across
// the existing per-k barrier (combine k-1 after step k's barrier) — no extra
// barriers. accY needs no exchange (each wave owns its dims).

typedef __attribute__((ext_vector_type(4))) float f32x4;
typedef __attribute__((ext_vector_type(8))) short bf16x8;  // 8 bf16 = 4 VGPRs

#define KC 32
#define NITER 10

typedef __attribute__((address_space(3))) void as3_void;
typedef __attribute__((address_space(1))) const void as1_cvoid;

static __device__ __forceinline__ void gl_lds16(const void* g, void* l) {
  __builtin_amdgcn_global_load_lds((as1_cvoid*)g, (as3_void*)l, 16, 0, 0);
}

static __device__ __forceinline__ unsigned pk_bf16(float a, float b) {
  __hip_bfloat16 ha = __float2bfloat16(a), hb = __float2bfloat16(b);
  unsigned short ua = *(unsigned short*)&ha, ub = *(unsigned short*)&hb;
  return (unsigned)ua | ((unsigned)ub << 16);
}

// ---------------- precompute 1 (verified in R1/R3): P = A^T A, Pmu, e, -----
// Psw in 16x16x32 A-frag order: idx = k*4096 + f*512 + lane*8 + j,
// f = MT*2 + s (MT in 0..3): val = P[s*32 + q*8 + j][MT*16 + l4]
__global__ void precompute1(const float* __restrict__ A, const float* __restrict__ mu,
                            const float* __restrict__ c,
                            float* __restrict__ Pmu_g, float* __restrict__ e_g,
                            __hip_bfloat16* __restrict__ Psw) {
  __shared__ float Pk[64 * 64];
  __shared__ float Pmu_s[64];
  const int k = blockIdx.x, tid = threadIdx.x;
  const float* Ak = A + k * 4096;
  for (int idx = tid; idx < 4096; idx += 256) {
    int i = idx >> 6, l = idx & 63;
    float s = 0.f;
    for (int j = 0; j < 64; ++j) s += Ak[j * 64 + i] * Ak[j * 64 + l];
    Pk[idx] = s;
  }
  __syncthreads();
  if (tid < 64) {
    float s = 0.f;
    for (int l = 0; l < 64; ++l) s += Pk[tid * 64 + l] * mu[k * 64 + l];
    Pmu_s[tid] = s;
    Pmu_g[k * 64 + tid] = s;
  }
  __syncthreads();
  if (tid == 0) {
    float s = 0.f;
    for (int i = 0; i < 64; ++i) s += mu[k * 64 + i] * Pmu_s[i];
    e_g[k] = c[k] - 0.5f * s;
  }
  for (int idx = tid; idx < 4096; idx += 256) {
    int f = idx >> 9, lane = (idx >> 3) & 63, j = idx & 7;
    int MT = f >> 1, s = f & 1, qq = lane >> 4, l4 = lane & 15;
    float v = Pk[(s * 32 + qq * 8 + j) * 64 + MT * 16 + l4];
    Psw[k * 4096 + idx] = __float2bfloat16(v);
  }
}

// ---------------- precompute 2 (verified in R1/R3): Pmu fragment swizzles --
__global__ void precompute2(const float* __restrict__ Pmu_g,
                            __hip_bfloat16* __restrict__ PmuA,
                            __hip_bfloat16* __restrict__ PmuB) {
  const int tid = threadIdx.x;
  // PmuA (pmx GEMM A): A[m=cluster][kk=dim]; frag f=(mtc,s)
  for (int idx = tid; idx < 2048; idx += 256) {
    int f = idx >> 9, lane = (idx >> 3) & 63, j = idx & 7;
    int mtc = f >> 1, s = f & 1, qq = lane >> 4, l4 = lane & 15;
    PmuA[idx] = __float2bfloat16(Pmu_g[(mtc * 16 + l4) * 64 + s * 32 + qq * 8 + j]);
  }
  // PmuB (pacc GEMM A): A[m=dim=f*16+l4][kk=cluster=q*8+j]
  for (int idx = tid; idx < 2048; idx += 256) {
    int f = idx >> 9, lane = (idx >> 3) & 63, j = idx & 7;
    int qq = lane >> 4, l4 = lane & 15;
    PmuB[idx] = __float2bfloat16(Pmu_g[(qq * 8 + j) * 64 + f * 16 + l4]);
  }
}

// ---------------- main kernel ----------------------------------------------
// 256 thr = 4 waves: wave = (d<<1)|g; g = pt-group (32 pts), d = dim-half
// (dims 32d..32d+31). Grid 1024 (64 pts/block) -> 4 blocks/CU, 16 waves/CU.
__launch_bounds__(256, 4)
__global__ void denoise_main(const float* __restrict__ x_in,
                             const float* __restrict__ e_g,
                             const float* __restrict__ alpha_g,
                             const __hip_bfloat16* __restrict__ Psw,
                             const __hip_bfloat16* __restrict__ PmuA,
                             const __hip_bfloat16* __restrict__ PmuB,
                             float* __restrict__ out) {
  __shared__ __attribute__((aligned(16))) char pbuf[2 * 8192];  // P dbuf 16 KB
  __shared__ __attribute__((aligned(16))) char xsg[2 * 4096];   // xstage/pmx 8 KB
  __shared__ __attribute__((aligned(16))) char wts[2 * 2048];   // weights 4 KB
  __shared__ float pxch[2 * 2 * 2 * 32];                        // dot partials 1 KB

  const int tid = threadIdx.x;
  const int wave = tid >> 6, lane = tid & 63;
  const int g = wave & 1, d = wave >> 1;
  const int q = lane >> 4, l4 = lane & 15;
  const int base_pt = blockIdx.x * 64 + g * 32;
  const float alpha = alpha_g[0];

  char* xs_g = xsg + g * 4096;                         // xstage (iter start) / pmx (k-loop)
  float* pmxw = (float*)xs_g;                          // [cl=32][pt=32] f32
  __hip_bfloat16* wtw = (__hip_bfloat16*)(wts + g * 2048);  // [pt=32][k=32] bf16

  const bf16x8* PmuAF = (const bf16x8*)PmuA;
  const bf16x8* PmuBF = (const bf16x8*)PmuB;

  // xm[mt][nt][r] = x[dim = d*32 + mt*16 + q*4 + r][pt = base_pt + nt*16 + l4]
  float xm[2][2][4];
#pragma unroll
  for (int mt = 0; mt < 2; ++mt)
#pragma unroll
    for (int nt = 0; nt < 2; ++nt) {
      f32x4 v = *(const f32x4*)&x_in[(base_pt + nt * 16 + l4) * 64 + d * 32 + mt * 16 + q * 4];
#pragma unroll
      for (int r = 0; r < 4; ++r) xm[mt][nt][r] = v[r];
    }

  const f32x4 Z4 = {0.f, 0.f, 0.f, 0.f};

#pragma unroll 1
  for (int it = 0; it < NITER; ++it) {
    // ---- 1. stage own dims of x (bf16) into shared rows [pt=32][dim=64],
    // 128 B rows, 16B-block XOR swizzle ----
#pragma unroll
    for (int mt = 0; mt < 2; ++mt)
#pragma unroll
      for (int nt = 0; nt < 2; ++nt) {
        unsigned u0 = pk_bf16(xm[mt][nt][0], xm[mt][nt][1]);
        unsigned u1 = pk_bf16(xm[mt][nt][2], xm[mt][nt][3]);
        int row = nt * 16 + l4;
        int blk = d * 4 + mt * 2 + (q >> 1);
        int addr = row * 128 + ((blk ^ (row & 7)) << 4) + (q & 1) * 8;
        uint2 v; v.x = u0; v.y = u1;
        *(uint2*)(xs_g + addr) = v;
      }
    __syncthreads();  // (A) x fully staged

    // ---- bx[ks][nt] = B[k=ks*32+q*8+j][n=pt=nt*16+l4] ----
    bf16x8 bx[2][2];
#pragma unroll
    for (int ks = 0; ks < 2; ++ks)
#pragma unroll
      for (int nt = 0; nt < 2; ++nt) {
        int row = nt * 16 + l4;
        int blk = ks * 4 + q;
        bx[ks][nt] = *(const bf16x8*)(xs_g + row * 128 + ((blk ^ (row & 7)) << 4));
      }

    // ---- DMA tile 0 into buf0 (each wave stages its 2 KB quarter) ----
    {
      const char* gp = (const char*)Psw + wave * 2048 + lane * 16;
      char* lp = pbuf + wave * 2048;
      gl_lds16(gp, lp);
      gl_lds16(gp + 1024, lp + 1024);
    }
    __syncthreads();  // (A2) all bx reads done; also drains tile-0 DMA

    // ---- pmx GEMM (both d compute; d==0 writes) ----
#pragma unroll
    for (int mtc = 0; mtc < 2; ++mtc)
#pragma unroll
      for (int nt = 0; nt < 2; ++nt) {
        f32x4 acc = Z4;
        acc = __builtin_amdgcn_mfma_f32_16x16x32_bf16(PmuAF[(mtc * 2 + 0) * 64 + lane], bx[0][nt], acc, 0, 0, 0);
        acc = __builtin_amdgcn_mfma_f32_16x16x32_bf16(PmuAF[(mtc * 2 + 1) * 64 + lane], bx[1][nt], acc, 0, 0, 0);
        if (d == 0) {
#pragma unroll
          for (int r = 0; r < 4; ++r)
            pmxw[(mtc * 16 + q * 4 + r) * 32 + nt * 16 + l4] = acc[r];
        }
      }

    float accY[2][2][4];
#pragma unroll
    for (int mt = 0; mt < 2; ++mt)
#pragma unroll
      for (int nt = 0; nt < 2; ++nt)
#pragma unroll
        for (int r = 0; r < 4; ++r) accY[mt][nt][r] = 0.f;
    float lsum0 = 0.f, lsum1 = 0.f;
    f32x4 yp[2][2];       // y of step k-1
    float pp0 = 0.f, pp1 = 0.f;  // own dot partials of step k-1

    // ---- step 0 (no barrier needed: A2 drained tile-0 DMA; prev iter's
    // buf1 readers are all past barrier A) ----
    {
      const char* gp = (const char*)Psw + 1 * 8192 + wave * 2048 + lane * 16;
      char* lp = pbuf + 8192 + wave * 2048;
      gl_lds16(gp, lp);
      gl_lds16(gp + 1024, lp + 1024);
      const char* pb = pbuf + d * 4096;
#pragma unroll
      for (int mt = 0; mt < 2; ++mt) {
        bf16x8 a0 = *(const bf16x8*)(pb + (mt * 2 + 0) * 1024 + lane * 16);
        bf16x8 a1 = *(const bf16x8*)(pb + (mt * 2 + 1) * 1024 + lane * 16);
#pragma unroll
        for (int nt = 0; nt < 2; ++nt) {
          f32x4 acc = __builtin_amdgcn_mfma_f32_16x16x32_bf16(a0, bx[0][nt], Z4, 0, 0, 0);
          acc = __builtin_amdgcn_mfma_f32_16x16x32_bf16(a1, bx[1][nt], acc, 0, 0, 0);
          yp[mt][nt] = acc;
        }
      }
      float p0 = 0.f, p1 = 0.f;
#pragma unroll
      for (int mt = 0; mt < 2; ++mt)
#pragma unroll
        for (int r = 0; r < 4; ++r) {
          p0 += xm[mt][0][r] * yp[mt][0][r];
          p1 += xm[mt][1][r] * yp[mt][1][r];
        }
      p0 += __shfl_xor(p0, 16, 64); p0 += __shfl_xor(p0, 32, 64);
      p1 += __shfl_xor(p1, 16, 64); p1 += __shfl_xor(p1, 32, 64);
      if (q == 0) {
        pxch[((0 * 2 + g) * 2 + d) * 32 + l4] = p0;
        pxch[((0 * 2 + g) * 2 + d) * 32 + 16 + l4] = p1;
      }
      pp0 = p0; pp1 = p1;
    }

    // ---- k-loop: steps 1..31; step k combines k-1 and computes k ----
#pragma unroll 2
    for (int k = 1; k < KC; ++k) {
      __syncthreads();  // tile k resident; partials k-1 visible; buf reuse safe
      if (k < KC - 1) {
        const char* gp = (const char*)Psw + (k + 1) * 8192 + wave * 2048 + lane * 16;
        char* lp = pbuf + ((k + 1) & 1) * 8192 + wave * 2048;
        gl_lds16(gp, lp);
        gl_lds16(gp + 1024, lp + 1024);
      }
      // ---- combine(k-1) ----
      {
        const int km1 = k - 1, par = km1 & 1;
        float xy0 = pp0 + pxch[((par * 2 + g) * 2 + (d ^ 1)) * 32 + l4];
        float xy1 = pp1 + pxch[((par * 2 + g) * 2 + (d ^ 1)) * 32 + 16 + l4];
        const float pk0 = pmxw[km1 * 32 + l4];
        const float pk1 = pmxw[km1 * 32 + 16 + l4];
        const float ek = e_g[km1];
        const float w0 = __expf(ek + pk0 - 0.5f * xy0);
        const float w1 = __expf(ek + pk1 - 0.5f * xy1);
        lsum0 += w0; lsum1 += w1;
        if (d == 0 && q == 0) {
          wtw[l4 * 32 + km1] = __float2bfloat16(w0);
          wtw[(16 + l4) * 32 + km1] = __float2bfloat16(w1);
        }
#pragma unroll
        for (int mt = 0; mt < 2; ++mt)
#pragma unroll
          for (int r = 0; r < 4; ++r) {
            accY[mt][0][r] += w0 * yp[mt][0][r];
            accY[mt][1][r] += w1 * yp[mt][1][r];
          }
      }
      // ---- compute(k) ----
      {
        const char* pb = pbuf + (k & 1) * 8192 + d * 4096;
#pragma unroll
        for (int mt = 0; mt < 2; ++mt) {
          bf16x8 a0 = *(const bf16x8*)(pb + (mt * 2 + 0) * 1024 + lane * 16);
          bf16x8 a1 = *(const bf16x8*)(pb + (mt * 2 + 1) * 1024 + lane * 16);
#pragma unroll
          for (int nt = 0; nt < 2; ++nt) {
            f32x4 acc = __builtin_amdgcn_mfma_f32_16x16x32_bf16(a0, bx[0][nt], Z4, 0, 0, 0);
            acc = __builtin_amdgcn_mfma_f32_16x16x32_bf16(a1, bx[1][nt], acc, 0, 0, 0);
            yp[mt][nt] = acc;
          }
        }
        float p0 = 0.f, p1 = 0.f;
#pragma unroll
        for (int mt = 0; mt < 2; ++mt)
#pragma unroll
          for (int r = 0; r < 4; ++r) {
            p0 += xm[mt][0][r] * yp[mt][0][r];
            p1 += xm[mt][1][r] * yp[mt][1][r];
          }
        p0 += __shfl_xor(p0, 16, 64); p0 += __shfl_xor(p0, 32, 64);
        p1 += __shfl_xor(p1, 16, 64); p1 += __shfl_xor(p1, 32, 64);
        if (q == 0) {
          pxch[(((k & 1) * 2 + g) * 2 + d) * 32 + l4] = p0;
          pxch[(((k & 1) * 2 + g) * 2 + d) * 32 + 16 + l4] = p1;
        }
        pp0 = p0; pp1 = p1;
      }
    }

    // ---- tail: combine(31) ----
    __syncthreads();
    {
      const int km1 = KC - 1, par = km1 & 1;
      float xy0 = pp0 + pxch[((par * 2 + g) * 2 + (d ^ 1)) * 32 + l4];
      float xy1 = pp1 + pxch[((par * 2 + g) * 2 + (d ^ 1)) * 32 + 16 + l4];
      const float pk0 = pmxw[km1 * 32 + l4];
      const float pk1 = pmxw[km1 * 32 + 16 + l4];
      const float ek = e_g[km1];
      const float w0 = __expf(ek + pk0 - 0.5f * xy0);
      const float w1 = __expf(ek + pk1 - 0.5f * xy1);
      lsum0 += w0; lsum1 += w1;
      if (d == 0 && q == 0) {
        wtw[l4 * 32 + km1] = __float2bfloat16(w0);
        wtw[(16 + l4) * 32 + km1] = __float2bfloat16(w1);
      }
#pragma unroll
      for (int mt = 0; mt < 2; ++mt)
#pragma unroll
        for (int r = 0; r < 4; ++r) {
          accY[mt][0][r] += w0 * yp[mt][0][r];
          accY[mt][1][r] += w1 * yp[mt][1][r];
        }
    }
    __syncthreads();  // (B) wtw complete

    // ---- pacc[dim][pt] for own dims (K=32 GEMM) + x update ----
    bf16x8 wtf[2];
#pragma unroll
    for (int nt = 0; nt < 2; ++nt)
      wtf[nt] = *(const bf16x8*)&wtw[(nt * 16 + l4) * 32 + q * 8];
    const float cc0 = alpha / lsum0;
    const float cc1 = alpha / lsum1;
#pragma unroll
    for (int mt = 0; mt < 2; ++mt) {
      bf16x8 a = PmuBF[(d * 2 + mt) * 64 + lane];
      f32x4 pa0 = __builtin_amdgcn_mfma_f32_16x16x32_bf16(a, wtf[0], Z4, 0, 0, 0);
      f32x4 pa1 = __builtin_amdgcn_mfma_f32_16x16x32_bf16(a, wtf[1], Z4, 0, 0, 0);
#pragma unroll
      for (int r = 0; r < 4; ++r) {
        xm[mt][0][r] += cc0 * (pa0[r] - accY[mt][0][r]);
        xm[mt][1][r] += cc1 * (pa1[r] - accY[mt][1][r]);
      }
    }
  }  // iterations

  // ---- output: own dims, f32x4 stores ----
#pragma unroll
  for (int mt = 0; mt < 2; ++mt)
#pragma unroll
    for (int nt = 0; nt < 2; ++nt) {
      f32x4 v;
#pragma unroll
      for (int r = 0; r < 4; ++r) v[r] = xm[mt][nt][r];
      *(f32x4*)&out[(base_pt + nt * 16 + l4) * 64 + d * 32 + mt * 16 + q * 4] = v;
    }
}

extern "C" void kernel_launch(void* const* d_in, const int* in_sizes, int n_in,
                              void* d_out, int out_size, void* d_ws, size_t ws_size,
                              hipStream_t stream) {
  (void)in_sizes; (void)n_in; (void)out_size; (void)ws_size;
  const float* x = (const float*)d_in[0];
  const float* c = (const float*)d_in[1];
  const float* mu = (const float*)d_in[2];
  const float* A = (const float*)d_in[3];
  const float* alpha = (const float*)d_in[4];
  float* out = (float*)d_out;

  char* ws = (char*)d_ws;
  float* Pmu_g = (float*)(ws);                           // 8192 B
  float* e_g = (float*)(ws + 8192);                      // 128 B (pad to 256)
  __hip_bfloat16* PmuA = (__hip_bfloat16*)(ws + 8448);   // 4096 B
  __hip_bfloat16* PmuB = (__hip_bfloat16*)(ws + 12544);  // 4096 B
  __hip_bfloat16* Psw = (__hip_bfloat16*)(ws + 16640);   // 262144 B

  precompute1<<<32, 256, 0, stream>>>(A, mu, c, Pmu_g, e_g, Psw);
  precompute2<<<1, 256, 0, stream>>>(Pmu_g, PmuA, PmuB);
  denoise_main<<<1024, 256, 0, stream>>>(x, e_g, alpha, Psw, PmuA, PmuB, out);
}

// Round 8
// 340.873 us; speedup vs baseline: 10.3274x; 10.3274x over previous
//
#include <hip/hip_runtime.h>
#include <hip/hip_bf16.h>

// DenoisingPotential: x_{t+1} = x_t + alpha * grad_phi(x_t), 10 iters.
// s_k = e_k + (Pmu_k . x) - 0.5*(x . y_k), y_k = P_k x
// x += (alpha/l) * (sum_k wt_k Pmu_k - sum_k wt_k y_k), wt = exp(s), l = sum wt
//
// R8: (256,4) is unreachable (unified VGPR+AGPR cap 128 -> spills, R4/R7).
// Design point is 8 waves/CU at (256,2); the win is per-k-step work:
// R3's barrier-free register-dbuf P skeleton + 32x32x16 MFMA (R6-verified
// layouts: 20% higher ceiling, half the MFMA insts, 1 shuffle not 2) +
// VALU diet (e_k folded into pmx spill, 0.5 folded into one fmaf, no
// accumulator copies, persistent zero). All LDS wave-private, no barriers.

typedef __attribute__((ext_vector_type(4))) float f32x4;
typedef __attribute__((ext_vector_type(16))) float f32x16;
typedef __attribute__((ext_vector_type(8))) short bf16x8;  // 8 bf16 = 4 VGPRs

#define KC 32
#define NITER 10
#define WAVE_SCR 6144  // per-wave scratch: xs/pmx 4096 + wt 2048

static __device__ __forceinline__ unsigned pk_bf16(float a, float b) {
  __hip_bfloat16 ha = __float2bfloat16(a), hb = __float2bfloat16(b);
  unsigned short ua = *(unsigned short*)&ha, ub = *(unsigned short*)&hb;
  return (unsigned)ua | ((unsigned)ub << 16);
}

// ---- precompute 1 (R6-verified): P = A^T A, Pmu, e, P in 32x32x16 A-frag
// order: Psw[k*4096 + f*512 + lane*8 + j], f = mt*4 + kf:
// val = P[kf*16 + (lane>>5)*8 + j][mt*32 + (lane&31)]
__global__ void precompute1(const float* __restrict__ A, const float* __restrict__ mu,
                            const float* __restrict__ c,
                            float* __restrict__ Pmu_g, float* __restrict__ e_g,
                            __hip_bfloat16* __restrict__ Psw) {
  __shared__ float Pk[64 * 64];
  __shared__ float Pmu_s[64];
  const int k = blockIdx.x, tid = threadIdx.x;
  const float* Ak = A + k * 4096;
  for (int idx = tid; idx < 4096; idx += 256) {
    int i = idx >> 6, l = idx & 63;
    float s = 0.f;
    for (int j = 0; j < 64; ++j) s += Ak[j * 64 + i] * Ak[j * 64 + l];
    Pk[idx] = s;
  }
  __syncthreads();
  if (tid < 64) {
    float s = 0.f;
    for (int l = 0; l < 64; ++l) s += Pk[tid * 64 + l] * mu[k * 64 + l];
    Pmu_s[tid] = s;
    Pmu_g[k * 64 + tid] = s;
  }
  __syncthreads();
  if (tid == 0) {
    float s = 0.f;
    for (int i = 0; i < 64; ++i) s += mu[k * 64 + i] * Pmu_s[i];
    e_g[k] = c[k] - 0.5f * s;
  }
  for (int idx = tid; idx < 4096; idx += 256) {
    int f = idx >> 9, lane = (idx >> 3) & 63, j = idx & 7;
    int mt = f >> 2, kf = f & 3, h = lane >> 5, l5 = lane & 31;
    float v = Pk[(kf * 16 + h * 8 + j) * 64 + mt * 32 + l5];
    Psw[k * 4096 + idx] = __float2bfloat16(v);
  }
}

// ---- precompute 2 (R6-verified): Pmu frags, 32x32x16 A-operand order ------
__global__ void precompute2(const float* __restrict__ Pmu_g,
                            __hip_bfloat16* __restrict__ PmuA,
                            __hip_bfloat16* __restrict__ PmuB) {
  const int tid = threadIdx.x;
  // PmuA (pmx GEMM A): A[m=cluster=lane&31][k=dim=f*16+h*8+j], f=kf (4 frags)
  for (int idx = tid; idx < 2048; idx += 256) {
    int f = idx >> 9, lane = (idx >> 3) & 63, j = idx & 7;
    int h = lane >> 5, l5 = lane & 31;
    PmuA[idx] = __float2bfloat16(Pmu_g[l5 * 64 + f * 16 + h * 8 + j]);
  }
  // PmuB (pacc GEMM A): A[m=dim=mt*32+(lane&31)][kk=cl=kf*16+h*8+j], f=mt*2+kf
  for (int idx = tid; idx < 2048; idx += 256) {
    int f = idx >> 9, lane = (idx >> 3) & 63, j = idx & 7;
    int mt = f >> 1, kf = f & 1, h = lane >> 5, l5 = lane & 31;
    PmuB[idx] = __float2bfloat16(Pmu_g[(kf * 16 + h * 8 + j) * 64 + mt * 32 + l5]);
  }
}

// ---- main: 256 thr (4 waves), 32 pts/wave, grid 512 (2 blocks/CU). --------
// No __syncthreads; LDS strictly wave-private; P register-double-buffered.
__launch_bounds__(256, 2)
__global__ void denoise_main(const float* __restrict__ x_in,
                             const float* __restrict__ e_g,
                             const float* __restrict__ alpha_g,
                             const __hip_bfloat16* __restrict__ Psw,
                             const __hip_bfloat16* __restrict__ PmuA,
                             const __hip_bfloat16* __restrict__ PmuB,
                             float* __restrict__ out) {
  __shared__ __attribute__((aligned(16))) char scratch[4 * WAVE_SCR];  // 24 KB

  const int tid = threadIdx.x;
  const int wave = tid >> 6, lane = tid & 63;
  const int h = lane >> 5, l5 = lane & 31;
  const int base_pt = blockIdx.x * 128 + wave * 32;
  const int pt = base_pt + l5;
  const float alpha = alpha_g[0];

  char* sw = scratch + wave * WAVE_SCR;
  float* pmxw = (float*)sw;                            // [cl=32][pt=32] f32 (overlays xs)
  __hip_bfloat16* wtw = (__hip_bfloat16*)(sw + 4096);  // [pt=32][k=32] bf16

  const bf16x8* PswF = (const bf16x8*)Psw;    // frag idx = k*512 + f*64 + lane
  const bf16x8* PmuAF = (const bf16x8*)PmuA;  // frag idx = f*64 + lane
  const bf16x8* PmuBF = (const bf16x8*)PmuB;

  // xm[mt][r] = x[dim = mt*32 + (r&3) + 8*(r>>2) + 4*h][pt]  (32x32 C-layout)
  float xm[2][16];
#pragma unroll
  for (int mt = 0; mt < 2; ++mt)
#pragma unroll
    for (int rq = 0; rq < 4; ++rq) {
      f32x4 v = *(const f32x4*)&x_in[pt * 64 + mt * 32 + rq * 8 + h * 4];
#pragma unroll
      for (int r = 0; r < 4; ++r) xm[mt][rq * 4 + r] = v[r];
    }

  // e values matching the pmx C-layout rows this lane spills (const, load once)
  float ev[16];
#pragma unroll
  for (int r = 0; r < 16; ++r) ev[r] = e_g[(r & 3) + 8 * (r >> 2) + 4 * h];

  const f32x16 Z16 = {0.f};

#pragma unroll 1
  for (int it = 0; it < NITER; ++it) {
    // ---- stage x (bf16) rows [pt=32][dim=64], 128 B rows, XOR-swizzled ----
#pragma unroll
    for (int mt = 0; mt < 2; ++mt)
#pragma unroll
      for (int rq = 0; rq < 4; ++rq) {
        unsigned u0 = pk_bf16(xm[mt][rq * 4 + 0], xm[mt][rq * 4 + 1]);
        unsigned u1 = pk_bf16(xm[mt][rq * 4 + 2], xm[mt][rq * 4 + 3]);
        int blk = mt * 4 + rq;
        int addr = l5 * 128 + ((blk ^ (l5 & 7)) << 4) + 8 * h;
        uint2 v; v.x = u0; v.y = u1;
        *(uint2*)(sw + addr) = v;
      }

    // ---- bx[kf] = B[k=kf*16+h*8+j][n=pt] ----
    bf16x8 bx[4];
#pragma unroll
    for (int kf = 0; kf < 4; ++kf) {
      int blk = 2 * kf + h;
      bx[kf] = *(const bf16x8*)(sw + l5 * 128 + ((blk ^ (l5 & 7)) << 4));
    }

    // ---- preload P(k=0) frags into register buffer 0 (overlaps pmx GEMM) --
    bf16x8 ap[2][8];
#pragma unroll
    for (int f = 0; f < 8; ++f) ap[0][f] = PswF[f * 64 + lane];

    // ---- pmx GEMM (one 32x32 tile, K=64), spill with e_k pre-folded ----
    {
      f32x16 acc = Z16;
#pragma unroll
      for (int kf = 0; kf < 4; ++kf)
        acc = __builtin_amdgcn_mfma_f32_32x32x16_bf16(PmuAF[kf * 64 + lane], bx[kf], acc, 0, 0, 0);
#pragma unroll
      for (int r = 0; r < 16; ++r) {
        int cl = (r & 3) + 8 * (r >> 2) + 4 * h;
        pmxw[cl * 32 + l5] = acc[r] + ev[r];
      }
    }

    float accY[2][16];
#pragma unroll
    for (int mt = 0; mt < 2; ++mt)
#pragma unroll
      for (int r = 0; r < 16; ++r) accY[mt][r] = 0.f;
    float lsum = 0.f;

    // ---- k-loop: register-dbuf P, no barriers ----
#pragma unroll 2
    for (int k = 0; k < KC; ++k) {
      const int cur = k & 1, nxt = cur ^ 1;
      const int kn = (k + 1) & (KC - 1);  // wraps harmlessly on last step
      // issue next-k fragment loads (overlap this step's compute)
#pragma unroll
      for (int f = 0; f < 8; ++f)
        ap[nxt][f] = PswF[kn * 512 + f * 64 + lane];

      // y = P x : two 32x32 tiles, K=64 (4 chained MFMAs each)
      f32x16 y0 = __builtin_amdgcn_mfma_f32_32x32x16_bf16(ap[cur][0], bx[0], Z16, 0, 0, 0);
      f32x16 y1 = __builtin_amdgcn_mfma_f32_32x32x16_bf16(ap[cur][4], bx[0], Z16, 0, 0, 0);
#pragma unroll
      for (int kf = 1; kf < 4; ++kf) {
        y0 = __builtin_amdgcn_mfma_f32_32x32x16_bf16(ap[cur][kf], bx[kf], y0, 0, 0, 0);
        y1 = __builtin_amdgcn_mfma_f32_32x32x16_bf16(ap[cur][4 + kf], bx[kf], y1, 0, 0, 0);
      }

      // xy = x . y : 32 in-lane FMAs (4 parallel chains), one shfl_xor(32)
      float p0 = xm[0][0] * y0[0], p1 = xm[0][1] * y0[1];
      float p2 = xm[0][2] * y0[2], p3 = xm[0][3] * y0[3];
#pragma unroll
      for (int r = 4; r < 16; r += 4) {
        p0 = fmaf(xm[0][r + 0], y0[r + 0], p0);
        p1 = fmaf(xm[0][r + 1], y0[r + 1], p1);
        p2 = fmaf(xm[0][r + 2], y0[r + 2], p2);
        p3 = fmaf(xm[0][r + 3], y0[r + 3], p3);
      }
#pragma unroll
      for (int r = 0; r < 16; r += 4) {
        p0 = fmaf(xm[1][r + 0], y1[r + 0], p0);
        p1 = fmaf(xm[1][r + 1], y1[r + 1], p1);
        p2 = fmaf(xm[1][r + 2], y1[r + 2], p2);
        p3 = fmaf(xm[1][r + 3], y1[r + 3], p3);
      }
      float xy = (p0 + p1) + (p2 + p3);
      xy += __shfl_xor(xy, 32, 64);

      // w = exp(e + pmx - 0.5*xy): e pre-folded into pmxw, 0.5 in one fmaf
      const float w = __expf(fmaf(-0.5f, xy, pmxw[k * 32 + l5]));
      lsum += w;
      if (h == 0) wtw[l5 * 32 + k] = __float2bfloat16(w);
#pragma unroll
      for (int r = 0; r < 16; ++r) {
        accY[0][r] = fmaf(w, y0[r], accY[0][r]);
        accY[1][r] = fmaf(w, y1[r], accY[1][r]);
      }
    }

    // ---- pacc[dim][pt] = sum_cl Pmu[cl][dim]*wt[cl][pt] (32x32, K=32) ----
    bf16x8 wtf[2];
#pragma unroll
    for (int kf = 0; kf < 2; ++kf)
      wtf[kf] = *(const bf16x8*)&wtw[l5 * 32 + kf * 16 + h * 8];
    const float cc = alpha / lsum;
#pragma unroll
    for (int mt = 0; mt < 2; ++mt) {
      f32x16 acc = __builtin_amdgcn_mfma_f32_32x32x16_bf16(PmuBF[(mt * 2 + 0) * 64 + lane], wtf[0], Z16, 0, 0, 0);
      acc = __builtin_amdgcn_mfma_f32_32x32x16_bf16(PmuBF[(mt * 2 + 1) * 64 + lane], wtf[1], acc, 0, 0, 0);
#pragma unroll
      for (int r = 0; r < 16; ++r)
        xm[mt][r] += cc * (acc[r] - accY[mt][r]);
    }
  }  // iterations

  // ---- output: 8x f32x4 direct stores ----
#pragma unroll
  for (int mt = 0; mt < 2; ++mt)
#pragma unroll
    for (int rq = 0; rq < 4; ++rq) {
      f32x4 v;
#pragma unroll
      for (int r = 0; r < 4; ++r) v[r] = xm[mt][rq * 4 + r];
      *(f32x4*)&out[pt * 64 + mt * 32 + rq * 8 + h * 4] = v;
    }
}

extern "C" void kernel_launch(void* const* d_in, const int* in_sizes, int n_in,
                              void* d_out, int out_size, void* d_ws, size_t ws_size,
                              hipStream_t stream) {
  (void)in_sizes; (void)n_in; (void)out_size; (void)ws_size;
  const float* x = (const float*)d_in[0];
  const float* c = (const float*)d_in[1];
  const float* mu = (const float*)d_in[2];
  const float* A = (const float*)d_in[3];
  const float* alpha = (const float*)d_in[4];
  float* out = (float*)d_out;

  char* ws = (char*)d_ws;
  float* Pmu_g = (float*)(ws);                           // 8192 B
  float* e_g = (float*)(ws + 8192);                      // 128 B (pad to 256)
  __hip_bfloat16* PmuA = (__hip_bfloat16*)(ws + 8448);   // 4096 B
  __hip_bfloat16* PmuB = (__hip_bfloat16*)(ws + 12544);  // 4096 B
  __hip_bfloat16* Psw = (__hip_bfloat16*)(ws + 16640);   // 262144 B

  precompute1<<<32, 256, 0, stream>>>(A, mu, c, Pmu_g, e_g, Psw);
  precompute2<<<1, 256, 0, stream>>>(Pmu_g, PmuA, PmuB);
  denoise_main<<<512, 256, 0, stream>>>(x, e_g, alpha, Psw, PmuA, PmuB, out);
}